// Round 1
// baseline (512.010 us; speedup 1.0000x reference)
//
#include <hip/hip_runtime.h>

#define D 64

// Phase 1: per-edge scatter-add. One thread per (edge, feature element).
// A 64-lane wave covers exactly one edge: src/dst loads are wave-uniform,
// the feature gather and the atomic destination are contiguous 256B blocks.
__global__ __launch_bounds__(256) void gcn_scatter(
    const float* __restrict__ feat,
    const int* __restrict__ src,
    const int* __restrict__ dst,
    float* __restrict__ summed,   // [N, 64] accumulator (pre-zeroed, aliased with d_out)
    float* __restrict__ deg,      // [N]
    int n_edges)
{
    int total = n_edges * D;            // 102.4M < 2^31
    int stride = gridDim.x * blockDim.x;
    for (int i = blockIdx.x * blockDim.x + threadIdx.x; i < total; i += stride) {
        int e = i >> 6;
        int j = i & 63;
        int s = src[e];
        int d = dst[e];
        atomicAdd(&summed[d * D + j], feat[s * D + j]);
        if (j == 0) atomicAdd(&deg[d], 1.0f);
    }
}

// Phase 2: per-node mean + deg-0 fallback + ReLU(h@W + b), one wave per node.
// W (16KB) staged in LDS; h broadcast across the wave via __shfl (no
// cross-wave barrier needed, so divergent grid-stride trip counts are safe).
__global__ __launch_bounds__(256) void gcn_node(
    const float* __restrict__ feat,
    const float* __restrict__ W,      // [64 in][64 out]
    const float* __restrict__ bias,   // [64]
    const float* __restrict__ deg,    // [N]
    float* __restrict__ inout,        // in: summed, out: final result (in-place)
    int n_nodes)
{
    __shared__ float Wl[D * D];
    int tid = threadIdx.x;
    for (int i = tid; i < D * D; i += 256) Wl[i] = W[i];
    __syncthreads();

    int lane = tid & 63;
    int wid  = tid >> 6;
    float bj = bias[lane];
    int nwaves = gridDim.x * 4;

    for (int n = blockIdx.x * 4 + wid; n < n_nodes; n += nwaves) {
        float dg = deg[n];
        float h = (dg > 0.0f) ? (inout[n * D + lane] / dg)
                              : feat[n * D + lane];
        float acc = bj;
        #pragma unroll
        for (int k = 0; k < D; ++k) {
            float hk = __shfl(h, k, 64);
            acc = fmaf(hk, Wl[k * D + lane], acc);
        }
        inout[n * D + lane] = fmaxf(acc, 0.0f);
    }
}

extern "C" void kernel_launch(void* const* d_in, const int* in_sizes, int n_in,
                              void* d_out, int out_size, void* d_ws, size_t ws_size,
                              hipStream_t stream)
{
    const float* feat = (const float*)d_in[0];
    const int*   src  = (const int*)d_in[1];
    const int*   dst  = (const int*)d_in[2];
    const float* W    = (const float*)d_in[3];
    const float* b    = (const float*)d_in[4];
    float* out = (float*)d_out;
    float* deg = (float*)d_ws;

    int n_nodes = in_sizes[0] / D;
    int n_edges = in_sizes[1];

    // Zero accumulators every call (harness poisons once, never re-zeroes).
    hipMemsetAsync(d_out, 0, (size_t)n_nodes * D * sizeof(float), stream);
    hipMemsetAsync(d_ws, 0, (size_t)n_nodes * sizeof(float), stream);

    gcn_scatter<<<4096, 256, 0, stream>>>(feat, src, dst, out, deg, n_edges);
    gcn_node<<<2048, 256, 0, stream>>>(feat, W, b, deg, out, n_nodes);
}

// Round 2
// 311.283 us; speedup vs baseline: 1.6448x; 1.6448x over previous
//
#include <hip/hip_runtime.h>

#define D 64

// ---------------- CSR-based path ----------------

// Pass A: degree histogram (int atomics, vectorized dst reads).
__global__ __launch_bounds__(256) void k_hist(
    const int* __restrict__ dst, int* __restrict__ cnt, int n_edges)
{
    int n4 = n_edges >> 2;
    const int4* d4 = (const int4*)dst;
    int stride = gridDim.x * blockDim.x;
    for (int i = blockIdx.x * blockDim.x + threadIdx.x; i < n4; i += stride) {
        int4 d = d4[i];
        atomicAdd(&cnt[d.x], 1);
        atomicAdd(&cnt[d.y], 1);
        atomicAdd(&cnt[d.z], 1);
        atomicAdd(&cnt[d.w], 1);
    }
    if (blockIdx.x == 0 && threadIdx.x == 0)
        for (int e = n4 << 2; e < n_edges; ++e) atomicAdd(&cnt[dst[e]], 1);
}

// Scan stage 1: each 256-thread block scans 1024 elements (4/thread).
__global__ __launch_bounds__(256) void k_scan1(
    const int* __restrict__ cnt, int* __restrict__ off,
    int* __restrict__ bsum, int n)
{
    int t = threadIdx.x, b = blockIdx.x;
    int base = b * 1024 + t * 4;
    int v0 = (base + 0 < n) ? cnt[base + 0] : 0;
    int v1 = (base + 1 < n) ? cnt[base + 1] : 0;
    int v2 = (base + 2 < n) ? cnt[base + 2] : 0;
    int v3 = (base + 3 < n) ? cnt[base + 3] : 0;
    int s = v0 + v1 + v2 + v3;
    int lane = t & 63;
    int incl = s;
    #pragma unroll
    for (int o = 1; o < 64; o <<= 1) {
        int u = __shfl_up(incl, o, 64);
        if (lane >= o) incl += u;
    }
    __shared__ int wtot[4];
    if (lane == 63) wtot[t >> 6] = incl;
    __syncthreads();
    int w = t >> 6;
    int wpre = 0;
    for (int i = 0; i < w; ++i) wpre += wtot[i];
    int excl = wpre + incl - s;   // exclusive prefix for this thread's chunk
    int p0 = excl + v0, p1 = p0 + v1, p2 = p1 + v2, p3 = p2 + v3;
    if (base + 0 < n) off[base + 1] = p0;
    if (base + 1 < n) off[base + 2] = p1;
    if (base + 2 < n) off[base + 3] = p2;
    if (base + 3 < n) off[base + 4] = p3;
    if (t == 255) bsum[b] = wpre + incl;   // block total
}

// Scan stage 2: exclusive scan of <=128 block sums, single block.
__global__ __launch_bounds__(128) void k_scan2(int* __restrict__ bsum, int nb)
{
    int t = threadIdx.x;
    int v = (t < nb) ? bsum[t] : 0;
    int lane = t & 63;
    int incl = v;
    #pragma unroll
    for (int o = 1; o < 64; o <<= 1) {
        int u = __shfl_up(incl, o, 64);
        if (lane >= o) incl += u;
    }
    __shared__ int wt[2];
    if (lane == 63) wt[t >> 6] = incl;
    __syncthreads();
    int add = (t >> 6) ? wt[0] : 0;
    int excl = add + incl - v;
    if (t < nb) bsum[t] = excl;
}

// Scan stage 3: add block prefixes; also init cursor = final exclusive offsets.
__global__ __launch_bounds__(256) void k_scan3(
    int* __restrict__ off, int* __restrict__ cursor,
    const int* __restrict__ bsum, int n)
{
    int t = threadIdx.x, b = blockIdx.x;
    int base = b * 1024 + t * 4;
    int add = bsum[b];
    #pragma unroll
    for (int i = 0; i < 4; ++i) {
        int idx = base + i;
        if (idx < n) {
            int v = off[idx + 1] + add;
            off[idx + 1] = v;
            if (idx + 1 < n) cursor[idx + 1] = v;
        }
    }
    if (b == 0 && t == 0) { off[0] = 0; cursor[0] = 0; }
}

// Pass C: scatter src ids into CSR slots.
__global__ __launch_bounds__(256) void k_scatter_csr(
    const int* __restrict__ src, const int* __restrict__ dst,
    int* __restrict__ cursor, int* __restrict__ csr, int n_edges)
{
    int n4 = n_edges >> 2;
    const int4* s4 = (const int4*)src;
    const int4* d4 = (const int4*)dst;
    int stride = gridDim.x * blockDim.x;
    for (int i = blockIdx.x * blockDim.x + threadIdx.x; i < n4; i += stride) {
        int4 s = s4[i];
        int4 d = d4[i];
        csr[atomicAdd(&cursor[d.x], 1)] = s.x;
        csr[atomicAdd(&cursor[d.y], 1)] = s.y;
        csr[atomicAdd(&cursor[d.z], 1)] = s.z;
        csr[atomicAdd(&cursor[d.w], 1)] = s.w;
    }
    if (blockIdx.x == 0 && threadIdx.x == 0)
        for (int e = n4 << 2; e < n_edges; ++e)
            csr[atomicAdd(&cursor[dst[e]], 1)] = src[e];
}

// Pass D: one wave per node — gather+sum, mean, deg-0 fallback, ReLU(hW+b).
__global__ __launch_bounds__(256) void k_node(
    const float* __restrict__ feat,
    const float* __restrict__ W,
    const float* __restrict__ bias,
    const int* __restrict__ off,
    const int* __restrict__ csr,
    float* __restrict__ out,
    int n_nodes)
{
    __shared__ float Wl[D * D];
    int tid = threadIdx.x;
    for (int i = tid; i < D * D; i += 256) Wl[i] = W[i];
    __syncthreads();

    int lane = tid & 63;
    int wid  = tid >> 6;
    float bj = bias[lane];
    int nwaves = gridDim.x * 4;

    for (int n = blockIdx.x * 4 + wid; n < n_nodes; n += nwaves) {
        int beg = off[n], end = off[n + 1];
        float acc = 0.0f;
        int i = beg;
        for (; i + 4 <= end; i += 4) {
            int s0 = csr[i], s1 = csr[i + 1], s2 = csr[i + 2], s3 = csr[i + 3];
            float f0 = feat[s0 * D + lane];
            float f1 = feat[s1 * D + lane];
            float f2 = feat[s2 * D + lane];
            float f3 = feat[s3 * D + lane];
            acc += f0 + f1 + f2 + f3;
        }
        for (; i < end; ++i) acc += feat[csr[i] * D + lane];

        int dg = end - beg;
        float h = (dg > 0) ? (acc / (float)dg) : feat[n * D + lane];

        float o = bj;
        #pragma unroll
        for (int k = 0; k < D; ++k) {
            float hk = __shfl(h, k, 64);
            o = fmaf(hk, Wl[k * D + lane], o);
        }
        out[n * D + lane] = fmaxf(o, 0.0f);
    }
}

// ---------------- fallback (R1 atomic path) ----------------

__global__ __launch_bounds__(256) void gcn_scatter(
    const float* __restrict__ feat, const int* __restrict__ src,
    const int* __restrict__ dst, float* __restrict__ summed,
    float* __restrict__ deg, int n_edges)
{
    int total = n_edges * D;
    int stride = gridDim.x * blockDim.x;
    for (int i = blockIdx.x * blockDim.x + threadIdx.x; i < total; i += stride) {
        int e = i >> 6, j = i & 63;
        atomicAdd(&summed[dst[e] * D + j], feat[src[e] * D + j]);
        if (j == 0) atomicAdd(&deg[dst[e]], 1.0f);
    }
}

__global__ __launch_bounds__(256) void gcn_node(
    const float* __restrict__ feat, const float* __restrict__ W,
    const float* __restrict__ bias, const float* __restrict__ deg,
    float* __restrict__ inout, int n_nodes)
{
    __shared__ float Wl[D * D];
    int tid = threadIdx.x;
    for (int i = tid; i < D * D; i += 256) Wl[i] = W[i];
    __syncthreads();
    int lane = tid & 63, wid = tid >> 6;
    float bj = bias[lane];
    int nwaves = gridDim.x * 4;
    for (int n = blockIdx.x * 4 + wid; n < n_nodes; n += nwaves) {
        float dg = deg[n];
        float h = (dg > 0.0f) ? (inout[n * D + lane] / dg) : feat[n * D + lane];
        float acc = bj;
        #pragma unroll
        for (int k = 0; k < D; ++k)
            acc = fmaf(__shfl(h, k, 64), Wl[k * D + lane], acc);
        inout[n * D + lane] = fmaxf(acc, 0.0f);
    }
}

// ---------------- host ----------------

extern "C" void kernel_launch(void* const* d_in, const int* in_sizes, int n_in,
                              void* d_out, int out_size, void* d_ws, size_t ws_size,
                              hipStream_t stream)
{
    const float* feat = (const float*)d_in[0];
    const int*   src  = (const int*)d_in[1];
    const int*   dst  = (const int*)d_in[2];
    const float* W    = (const float*)d_in[3];
    const float* b    = (const float*)d_in[4];
    float* out = (float*)d_out;

    int n_nodes = in_sizes[0] / D;
    int n_edges = in_sizes[1];

    // ws layout (ints), 64B-aligned regions:
    //   cnt/cursor [N] | off [N+1] | bsum [128] | csr [E]
    size_t cnt_off  = 0;
    size_t off_off  = (((size_t)n_nodes * 4) + 63) & ~(size_t)63;
    size_t bsum_off = (off_off + ((size_t)n_nodes + 1) * 4 + 63) & ~(size_t)63;
    size_t csr_off  = (bsum_off + 128 * 4 + 63) & ~(size_t)63;
    size_t need     = csr_off + (size_t)n_edges * 4;
    int nb = (n_nodes + 1023) / 1024;

    if (ws_size >= need && nb <= 128) {
        char* ws = (char*)d_ws;
        int* cnt    = (int*)(ws + cnt_off);   // reused as cursor after scan
        int* off    = (int*)(ws + off_off);
        int* bsum   = (int*)(ws + bsum_off);
        int* csr    = (int*)(ws + csr_off);

        hipMemsetAsync(cnt, 0, (size_t)n_nodes * 4, stream);
        k_hist<<<1024, 256, 0, stream>>>(dst, cnt, n_edges);
        k_scan1<<<nb, 256, 0, stream>>>(cnt, off, bsum, n_nodes);
        k_scan2<<<1, 128, 0, stream>>>(bsum, nb);
        k_scan3<<<nb, 256, 0, stream>>>(off, cnt /*cursor*/, bsum, n_nodes);
        k_scatter_csr<<<1024, 256, 0, stream>>>(src, dst, cnt /*cursor*/, csr, n_edges);
        k_node<<<2048, 256, 0, stream>>>(feat, W, b, off, csr, out, n_nodes);
    } else {
        // fallback: R1 atomic path
        float* deg = (float*)d_ws;
        hipMemsetAsync(d_out, 0, (size_t)n_nodes * D * sizeof(float), stream);
        hipMemsetAsync(d_ws, 0, (size_t)n_nodes * sizeof(float), stream);
        gcn_scatter<<<4096, 256, 0, stream>>>(feat, src, dst, out, deg, n_edges);
        gcn_node<<<2048, 256, 0, stream>>>(feat, W, b, deg, out, n_nodes);
    }
}